// Round 11
// baseline (66.610 us; speedup 1.0000x reference)
//
#include <hip/hip_runtime.h>
#include <hip/hip_fp16.h>

typedef _Float16 half8 __attribute__((ext_vector_type(8)));
typedef _Float16 half4v __attribute__((ext_vector_type(4)));
typedef float float4v __attribute__((ext_vector_type(4)));

#define E_DIM 300
#define KP 320               // padded K (10 MFMA k-steps of 32)
#define B_ 32
#define NROW_CDD 3200        // 32*5*20
#define NROW_HIS 32000       // 32*50*20

// ---------------- Kernel 1: gather + l2-normalize -> fp16 rows (K padded to 320) --------
__global__ __launch_bounds__(256) void gather_norm(const int* __restrict__ cand,
                                                   const int* __restrict__ clk,
                                                   const float* __restrict__ emb,
                                                   _Float16* __restrict__ outH)
{
    int row  = blockIdx.x * 4 + (threadIdx.x >> 6);
    int lane = threadIdx.x & 63;
    int tok = (row < NROW_CDD) ? cand[row] : clk[row - NROW_CDD];
    const float* e = emb + (long)tok * E_DIM;
    float v[5];
    float ss = 0.f;
#pragma unroll
    for (int j = 0; j < 5; ++j) {
        int idx = lane + j * 64;
        float x = (idx < E_DIM) ? e[idx] : 0.f;
        v[j] = x;
        ss += x * x;
    }
#pragma unroll
    for (int off = 32; off; off >>= 1) ss += __shfl_xor(ss, off);
    float scale = 1.0f / fmaxf(sqrtf(ss), 1e-12f);
    _Float16* o = outH + (long)row * KP;
#pragma unroll
    for (int j = 0; j < 5; ++j) {
        int idx = lane + j * 64;
        o[idx] = (_Float16)((idx < E_DIM) ? v[j] * scale : 0.f);
    }
}

// ---------------- Kernel 2: pure-wave LDS-free sim GEMM --------------------------------
// One 16x16 output tile per wave. No LDS, no barriers, 20 hoisted loads then 10 MFMAs.
// grid (111, 32): wave-tile wt = bx*4+wave in [0,441) = 7 mtiles x 63 ntiles.
__global__ __launch_bounds__(256, 4) void sim_gemm(const _Float16* __restrict__ wsH,
                                                   _Float16* __restrict__ simW)
{
    int b = blockIdx.y;
    int tid = threadIdx.x;
    int wave = tid >> 6, lane = tid & 63;
    int g = lane >> 4, r16 = lane & 15;

    int wt = blockIdx.x * 4 + wave;
    if (wt >= 441) return;                 // wave-uniform exit, no barriers in kernel
    int m = wt / 63, n = wt - m * 63;

    int rA = m * 16 + r16; if (rA > 99) rA = 99;
    int rB = n * 16 + r16; if (rB > 999) rB = 999;
    const char* pA = (const char*)(wsH + (size_t)(b * 100 + rA) * KP);
    const char* pB = (const char*)(wsH + (size_t)(NROW_CDD + b * 1000 + rB) * KP);

    // hoist all fragment loads (independent -> deep MLP)
    half8 af[10], bf[10];
#pragma unroll
    for (int k = 0; k < 10; ++k) {
        af[k] = *(const half8*)(pA + k * 64 + g * 16);
        bf[k] = *(const half8*)(pB + k * 64 + g * 16);
    }

    float4v acc = (float4v){0.f, 0.f, 0.f, 0.f};
#pragma unroll
    for (int k = 0; k < 10; ++k)
        acc = __builtin_amdgcn_mfma_f32_16x16x32_f16(af[k], bf[k], acc, 0, 0, 0);

    // C/D layout (validated r1-r10): col = lane&15 (B-row), row = (lane>>4)*4+j (A-row)
    int col = n * 16 + r16;
    if (col > 999) return;
    size_t obase = (size_t)b * 100000;
#pragma unroll
    for (int j = 0; j < 4; ++j) {
        int r = m * 16 + g * 4 + j;
        if (r < 100) simW[obase + (size_t)r * 1000 + col] = (_Float16)acc[j];
    }
}

// ---------------- Kernel 3: gaussian kernels + log pooling, one block per sim row -------
// grid 3200, 256 threads (250 active: h=tid%50, kq=tid/50, 4 k's each). LDS 12.6 KB.
__global__ __launch_bounds__(256) void knrm_pool(const _Float16* __restrict__ simW,
                                                 const float* __restrict__ cpad,
                                                 const float* __restrict__ hpad,
                                                 const float* __restrict__ ltr_w,
                                                 float* __restrict__ rowsum)
{
    __shared__ float sS[50 * 21];
    __shared__ float mS[50 * 21];
    __shared__ float wS[1000];
    __shared__ float part[4];

    int row = blockIdx.x;            // (b*5+c)*20 + s
    int b = row / 100;
    int tid = threadIdx.x;

    if (tid < 250) {
        int p = tid * 4;
        half4v hv = *(const half4v*)(simW + (size_t)row * 1000 + p);
        float4v mv = *(const float4v*)(hpad + (size_t)b * 1000 + p);
        *(float4v*)&wS[p] = *(const float4v*)(ltr_w + p);
#pragma unroll
        for (int q = 0; q < 4; ++q) {
            int pq = p + q, h = pq / 20, t = pq - h * 20;
            sS[h * 21 + t] = (float)hv[q];
            mS[h * 21 + t] = mv[q];
        }
    }
    __syncthreads();

    float val = 0.f;
    if (tid < 250) {
        int h = tid % 50, kq = tid / 50;     // kq 0..4, k = kq*4+j
        float bj[4], cj[4];
        bool is19[4];
#pragma unroll
        for (int j = 0; j < 4; ++j) {
            float mu = -0.9f + 0.1f * (float)(kq * 4 + j);
            bj[j] = 100.0f * mu;
            cj[j] = -50.0f * mu * mu;
            is19[j] = (kq * 4 + j) == 19;
        }
        float psum0 = 0.f, psum1 = 0.f, psum2 = 0.f, psum3 = 0.f;
        const float* sp = sS + h * 21;
        const float* mp = mS + h * 21;
#pragma unroll 4
        for (int t = 0; t < 20; ++t) {
            float s  = sp[t];
            float mm = mp[t];
            float d  = s - 1.0f;
            float arg19 = -500000.0f * d * d;
            float a0 = is19[0] ? arg19 : fmaf(fmaf(-50.0f, s, bj[0]), s, cj[0]);
            float a1 = is19[1] ? arg19 : fmaf(fmaf(-50.0f, s, bj[1]), s, cj[1]);
            float a2 = is19[2] ? arg19 : fmaf(fmaf(-50.0f, s, bj[2]), s, cj[2]);
            float a3 = is19[3] ? arg19 : fmaf(fmaf(-50.0f, s, bj[3]), s, cj[3]);
            psum0 = fmaf(__expf(a0), mm, psum0);
            psum1 = fmaf(__expf(a1), mm, psum1);
            psum2 = fmaf(__expf(a2), mm, psum2);
            psum3 = fmaf(__expf(a3), mm, psum3);
        }
        const float* wp = wS + h * 20 + kq * 4;
        val  = __logf(fmaxf(psum0, 1e-10f)) * wp[0];
        val += __logf(fmaxf(psum1, 1e-10f)) * wp[1];
        val += __logf(fmaxf(psum2, 1e-10f)) * wp[2];
        val += __logf(fmaxf(psum3, 1e-10f)) * wp[3];
    }
#pragma unroll
    for (int off = 32; off; off >>= 1) val += __shfl_down(val, off);
    int wave = tid >> 6, lane = tid & 63;
    if (lane == 0) part[wave] = val;
    __syncthreads();
    if (tid == 0)
        rowsum[row] = (part[0] + part[1] + part[2] + part[3]) * 0.01f * cpad[row];
}

// ---------------- Kernel 4: sum rows per (b,c) + bias + log_softmax over C=5 ------------
__global__ __launch_bounds__(64) void finalize(const float* __restrict__ rowsum,
                                               const float* __restrict__ ltr_b,
                                               float* __restrict__ out)
{
    int b = blockIdx.x;
    int tid = threadIdx.x;
    __shared__ float sc[5];
    if (tid < 5) {
        float a = ltr_b[0];
        const float* rp = rowsum + (b * 5 + tid) * 20;
#pragma unroll
        for (int s = 0; s < 20; ++s) a += rp[s];
        sc[tid] = a;
    }
    __syncthreads();
    if (tid < 5) {
        float m = fmaxf(fmaxf(fmaxf(sc[0], sc[1]), fmaxf(sc[2], sc[3])), sc[4]);
        float sum = 0.f;
#pragma unroll
        for (int i = 0; i < 5; ++i) sum += __expf(sc[i] - m);
        out[b * 5 + tid] = sc[tid] - m - __logf(sum);
    }
}

extern "C" void kernel_launch(void* const* d_in, const int* in_sizes, int n_in,
                              void* d_out, int out_size, void* d_ws, size_t ws_size,
                              hipStream_t stream)
{
    const int*   cand = (const int*)d_in[0];
    const int*   clk  = (const int*)d_in[1];
    const float* cpad = (const float*)d_in[2];
    const float* hpad = (const float*)d_in[3];
    const float* emb  = (const float*)d_in[4];
    const float* lw   = (const float*)d_in[5];
    const float* lb   = (const float*)d_in[6];
    float* out = (float*)d_out;

    _Float16* wsH  = (_Float16*)d_ws;                                                   // 22.528 MB
    _Float16* simW = (_Float16*)((char*)d_ws + (size_t)(NROW_CDD + NROW_HIS) * KP * 2); // 6.4 MB
    float* rowsum  = (float*)((char*)simW + (size_t)B_ * 100 * 1000 * 2);               // 12.8 KB

    hipLaunchKernelGGL(gather_norm, dim3((NROW_CDD + NROW_HIS) / 4), dim3(256), 0, stream,
                       cand, clk, emb, wsH);
    hipLaunchKernelGGL(sim_gemm, dim3(111, B_), dim3(256), 0, stream, wsH, simW);
    hipLaunchKernelGGL(knrm_pool, dim3(NROW_CDD), dim3(256), 0, stream,
                       simW, cpad, hpad, lw, rowsum);
    hipLaunchKernelGGL(finalize, dim3(B_), dim3(64), 0, stream, rowsum, lb, out);
}

// Round 12
// 46.489 us; speedup vs baseline: 1.4328x; 1.4328x over previous
//
#include <hip/hip_runtime.h>
#include <hip/hip_fp16.h>

typedef _Float16 half8 __attribute__((ext_vector_type(8)));
typedef _Float16 half4v __attribute__((ext_vector_type(4)));
typedef float float4v __attribute__((ext_vector_type(4)));

#define E_DIM 300
#define KP 320               // padded K (10 MFMA k-steps of 32)
#define B_ 32
#define NROW_CDD 3200        // 32*5*20
#define NROW_HIS 32000       // 32*50*20

// ---------------- Kernel 1: gather + l2-normalize -> fp16 rows (K padded to 320) --------
__global__ __launch_bounds__(256) void gather_norm(const int* __restrict__ cand,
                                                   const int* __restrict__ clk,
                                                   const float* __restrict__ emb,
                                                   _Float16* __restrict__ outH)
{
    int row  = blockIdx.x * 4 + (threadIdx.x >> 6);
    int lane = threadIdx.x & 63;
    int tok = (row < NROW_CDD) ? cand[row] : clk[row - NROW_CDD];
    const float* e = emb + (long)tok * E_DIM;
    float v[5];
    float ss = 0.f;
#pragma unroll
    for (int j = 0; j < 5; ++j) {
        int idx = lane + j * 64;
        float x = (idx < E_DIM) ? e[idx] : 0.f;
        v[j] = x;
        ss += x * x;
    }
#pragma unroll
    for (int off = 32; off; off >>= 1) ss += __shfl_xor(ss, off);
    float scale = 1.0f / fmaxf(sqrtf(ss), 1e-12f);
    _Float16* o = outH + (long)row * KP;
#pragma unroll
    for (int j = 0; j < 5; ++j) {
        int idx = lane + j * 64;
        o[idx] = (_Float16)((idx < E_DIM) ? v[j] * scale : 0.f);
    }
}

// ---------------- Kernel 2: sim GEMM, two-phase staged (full MLP), linear+XOR LDS -------
// grid (8, 32) = 256 blocks (1/CU), 512 threads (8 waves: 2 wm x 4 wn).
// Staging: 18 independent uint4 loads hoisted into regs, THEN 18 LDS writes.
// LDS: linear 640-B rows, byte ^ ((row&7)<<4) swizzle -> bank-balanced ds_read_b128.
__global__ __launch_bounds__(512, 1) void sim_gemm(const _Float16* __restrict__ wsH,
                                                   _Float16* __restrict__ simW)
{
    __shared__ __align__(16) char Abuf[100 * 640];     // 64000 B, linear rows
    __shared__ __align__(16) char Bbuf[125 * 640];     // 80000 B
    float* simT = (float*)Abuf;                        // overlay after GEMM: 100*132*4

    int b = blockIdx.y, ntile = blockIdx.x;
    int tid = threadIdx.x;
    int wave = tid >> 6, lane = tid & 63;
    int wm = wave >> 2, wn = wave & 3;
    int g = lane >> 4, r16 = lane & 15;

    const char* gA = (const char*)(wsH + (size_t)b * 100 * KP);
    const char* gB = (const char*)(wsH + (size_t)(NROW_CDD + b * 1000 + ntile * 125) * KP);

    // ---- phase 1: issue ALL independent loads (clamped; no LDS writes in between) ----
    uint4 av[8], bv[10];
#pragma unroll
    for (int j = 0; j < 8; ++j) {
        int u = tid + 512 * j; if (u > 3999) u = 3999;
        av[j] = *(const uint4*)(gA + (size_t)u * 16);
    }
#pragma unroll
    for (int j = 0; j < 10; ++j) {
        int u = tid + 512 * j; if (u > 4999) u = 4999;
        bv[j] = *(const uint4*)(gB + (size_t)u * 16);
    }

    // ---- phase 2: LDS writes (predicated), swizzled: byte ^ ((row&7)<<4) ----
#pragma unroll
    for (int j = 0; j < 8; ++j) {
        int u = tid + 512 * j;
        if (u < 4000) {
            int r = u / 40;
            *(uint4*)(Abuf + ((u * 16) ^ ((r & 7) << 4))) = av[j];
        }
    }
#pragma unroll
    for (int j = 0; j < 10; ++j) {
        int u = tid + 512 * j;
        if (u < 5000) {
            int r = u / 40;
            *(uint4*)(Bbuf + ((u * 16) ^ ((r & 7) << 4))) = bv[j];
        }
    }
    __syncthreads();

    // ---- MFMA: 100x125 tile, both operands from swizzled LDS ----
    float4v acc[4][2];
#pragma unroll
    for (int m = 0; m < 4; ++m)
#pragma unroll
        for (int n = 0; n < 2; ++n) acc[m][n] = (float4v){0.f, 0.f, 0.f, 0.f};

#pragma unroll 2
    for (int k = 0; k < 10; ++k) {
        half8 bf[2];
#pragma unroll
        for (int n = 0; n < 2; ++n) {
            int rB = wn * 32 + n * 16 + r16; if (rB > 124) rB = 124;
            bf[n] = *(const half8*)(Bbuf + ((rB * 640 + k * 64 + g * 16) ^ ((rB & 7) << 4)));
        }
#pragma unroll
        for (int m = 0; m < 4; ++m) {
            int rA = wm * 64 + m * 16 + r16; if (rA > 99) rA = 99;
            half8 af = *(const half8*)(Abuf + ((rA * 640 + k * 64 + g * 16) ^ ((rA & 7) << 4)));
#pragma unroll
            for (int n = 0; n < 2; ++n)
                acc[m][n] = __builtin_amdgcn_mfma_f32_16x16x32_f16(af, bf[n], acc[m][n], 0, 0, 0);
        }
    }
    __syncthreads();   // all waves done reading Abuf before overlay

    // C/D layout (validated r1-r11): col = lane&15 (B-row), row = (lane>>4)*4+j (A-row)
#pragma unroll
    for (int m = 0; m < 4; ++m) {
        int rowb = wm * 64 + m * 16 + g * 4;
#pragma unroll
        for (int n = 0; n < 2; ++n) {
            int col = wn * 32 + n * 16 + r16;
            if (col < 125) {
#pragma unroll
                for (int j = 0; j < 4; ++j) {
                    int r = rowb + j;
                    if (r < 100) simT[r * 132 + col] = acc[m][n][j];
                }
            }
        }
    }
    __syncthreads();

    // coalesced fp16 write-out: 100 rows x 125 cols
    size_t obase = (size_t)b * 100000 + (size_t)ntile * 125;
    for (int u = tid; u < 12500; u += 512) {
        int r = u / 125, c = u - r * 125;
        simW[obase + (size_t)r * 1000 + c] = (_Float16)simT[r * 132 + c];
    }
}

// ---------------- Kernel 3: gaussian kernels + log pooling, one block per sim row -------
// grid 3200, 256 threads (250 active: h=tid%50, kq=tid/50, 4 k's each). LDS 12.6 KB.
__global__ __launch_bounds__(256) void knrm_pool(const _Float16* __restrict__ simW,
                                                 const float* __restrict__ cpad,
                                                 const float* __restrict__ hpad,
                                                 const float* __restrict__ ltr_w,
                                                 float* __restrict__ rowsum)
{
    __shared__ float sS[50 * 21];
    __shared__ float mS[50 * 21];
    __shared__ float wS[1000];
    __shared__ float part[4];

    int row = blockIdx.x;            // (b*5+c)*20 + s
    int b = row / 100;
    int tid = threadIdx.x;

    if (tid < 250) {
        int p = tid * 4;
        half4v hv = *(const half4v*)(simW + (size_t)row * 1000 + p);
        float4v mv = *(const float4v*)(hpad + (size_t)b * 1000 + p);
        *(float4v*)&wS[p] = *(const float4v*)(ltr_w + p);
#pragma unroll
        for (int q = 0; q < 4; ++q) {
            int pq = p + q, h = pq / 20, t = pq - h * 20;
            sS[h * 21 + t] = (float)hv[q];
            mS[h * 21 + t] = mv[q];
        }
    }
    __syncthreads();

    float val = 0.f;
    if (tid < 250) {
        int h = tid % 50, kq = tid / 50;     // kq 0..4, k = kq*4+j
        float bj[4], cj[4];
        bool is19[4];
#pragma unroll
        for (int j = 0; j < 4; ++j) {
            float mu = -0.9f + 0.1f * (float)(kq * 4 + j);
            bj[j] = 100.0f * mu;
            cj[j] = -50.0f * mu * mu;
            is19[j] = (kq * 4 + j) == 19;
        }
        float psum0 = 0.f, psum1 = 0.f, psum2 = 0.f, psum3 = 0.f;
        const float* sp = sS + h * 21;
        const float* mp = mS + h * 21;
#pragma unroll 4
        for (int t = 0; t < 20; ++t) {
            float s  = sp[t];
            float mm = mp[t];
            float d  = s - 1.0f;
            float arg19 = -500000.0f * d * d;
            float a0 = is19[0] ? arg19 : fmaf(fmaf(-50.0f, s, bj[0]), s, cj[0]);
            float a1 = is19[1] ? arg19 : fmaf(fmaf(-50.0f, s, bj[1]), s, cj[1]);
            float a2 = is19[2] ? arg19 : fmaf(fmaf(-50.0f, s, bj[2]), s, cj[2]);
            float a3 = is19[3] ? arg19 : fmaf(fmaf(-50.0f, s, bj[3]), s, cj[3]);
            psum0 = fmaf(__expf(a0), mm, psum0);
            psum1 = fmaf(__expf(a1), mm, psum1);
            psum2 = fmaf(__expf(a2), mm, psum2);
            psum3 = fmaf(__expf(a3), mm, psum3);
        }
        const float* wp = wS + h * 20 + kq * 4;
        val  = __logf(fmaxf(psum0, 1e-10f)) * wp[0];
        val += __logf(fmaxf(psum1, 1e-10f)) * wp[1];
        val += __logf(fmaxf(psum2, 1e-10f)) * wp[2];
        val += __logf(fmaxf(psum3, 1e-10f)) * wp[3];
    }
#pragma unroll
    for (int off = 32; off; off >>= 1) val += __shfl_down(val, off);
    int wave = tid >> 6, lane = tid & 63;
    if (lane == 0) part[wave] = val;
    __syncthreads();
    if (tid == 0)
        rowsum[row] = (part[0] + part[1] + part[2] + part[3]) * 0.01f * cpad[row];
}

// ---------------- Kernel 4: sum rows per (b,c) + bias + log_softmax over C=5 ------------
__global__ __launch_bounds__(64) void finalize(const float* __restrict__ rowsum,
                                               const float* __restrict__ ltr_b,
                                               float* __restrict__ out)
{
    int b = blockIdx.x;
    int tid = threadIdx.x;
    __shared__ float sc[5];
    if (tid < 5) {
        float a = ltr_b[0];
        const float* rp = rowsum + (b * 5 + tid) * 20;
#pragma unroll
        for (int s = 0; s < 20; ++s) a += rp[s];
        sc[tid] = a;
    }
    __syncthreads();
    if (tid < 5) {
        float m = fmaxf(fmaxf(fmaxf(sc[0], sc[1]), fmaxf(sc[2], sc[3])), sc[4]);
        float sum = 0.f;
#pragma unroll
        for (int i = 0; i < 5; ++i) sum += __expf(sc[i] - m);
        out[b * 5 + tid] = sc[tid] - m - __logf(sum);
    }
}

extern "C" void kernel_launch(void* const* d_in, const int* in_sizes, int n_in,
                              void* d_out, int out_size, void* d_ws, size_t ws_size,
                              hipStream_t stream)
{
    const int*   cand = (const int*)d_in[0];
    const int*   clk  = (const int*)d_in[1];
    const float* cpad = (const float*)d_in[2];
    const float* hpad = (const float*)d_in[3];
    const float* emb  = (const float*)d_in[4];
    const float* lw   = (const float*)d_in[5];
    const float* lb   = (const float*)d_in[6];
    float* out = (float*)d_out;

    _Float16* wsH  = (_Float16*)d_ws;                                                   // 22.528 MB
    _Float16* simW = (_Float16*)((char*)d_ws + (size_t)(NROW_CDD + NROW_HIS) * KP * 2); // 6.4 MB
    float* rowsum  = (float*)((char*)simW + (size_t)B_ * 100 * 1000 * 2);               // 12.8 KB

    hipLaunchKernelGGL(gather_norm, dim3((NROW_CDD + NROW_HIS) / 4), dim3(256), 0, stream,
                       cand, clk, emb, wsH);
    hipLaunchKernelGGL(sim_gemm, dim3(8, B_), dim3(512), 0, stream, wsH, simW);
    hipLaunchKernelGGL(knrm_pool, dim3(NROW_CDD), dim3(256), 0, stream,
                       simW, cpad, hpad, lw, rowsum);
    hipLaunchKernelGGL(finalize, dim3(B_), dim3(64), 0, stream, rowsum, lb, out);
}